// Round 2
// 111.516 us; speedup vs baseline: 1.0014x; 1.0014x over previous
//
#include <hip/hip_runtime.h>
#include <math.h>

#define NUM_GRAPHS 512
#define D 128
#define HDIM 256

// native clang vector type: __builtin_nontemporal_load requires a pointer to
// scalar or vector-of-scalar, NOT HIP_vector_type<float,4> (R11 compile fail)
typedef float f4 __attribute__((ext_vector_type(4)));

// ---------------------------------------------------------------------------
// FUSED single-kernel version (R11b). Previous best (110 us) was
// seg_sum(4096 blocks) + mlp_scatter(256 blocks) through a 2 MB partial
// buffer. rocprof showed both kernels < 42 us (below the harness's 256 MiB
// ws-poison fill in top-5); est. 15-20 us combined vs ~90 us harness-fixed
// cost. This round: one block per graph does bounds+sum+MLP+scatter.
//   - eliminates 1 launch, the 2 MB partial write+read, bounds publish,
//     and the K=8 reduce pass in the MLP kernel
//   - workspace now entirely unused (poison fill remains, harness-owned)
//   - sum phase at 8 waves/CU: unroll-4 float4 keeps 32 KB/CU in flight
//     (> ~9.2 KB needed by Little's law at 900cy HBM latency)
// ---------------------------------------------------------------------------

// O(1) int32-vs-int64 detection for the sorted batch array (proven R-prev).
__device__ __forceinline__ int detect_is64(const int* __restrict__ b, int N)
{
    const int j = ((N - 1) & 1) ? (N - 1) : (N - 2);
    return b[j] == 0;
}

// Wave-parallel 64-ary lower_bound: 3 rounds for N=1e5 (proven R-prev;
// binary search was +5.8us in R9).
__device__ __forceinline__ int wave_lower_bound(const int* __restrict__ b32,
                                                int is64, int N, int target,
                                                int lane)
{
    const long long* b64 = (const long long*)b32;
    int lo = 0, hi = N;
    while (hi > lo) {
        const int len  = hi - lo;
        const int step = (len + 63) >> 6;
        const int p    = lo + lane * step;
        int lt = 0;
        if (p < hi) {
            int v = is64 ? (int)b64[p] : b32[p];
            lt = (v < target);
        }
        unsigned long long m = __ballot(lt);
        int cnt = __popcll(m);
        if (cnt == 0) { hi = lo; break; }          // b[lo] >= target
        int nlo = lo + (cnt - 1) * step + 1;        // b[nlo-1] < target
        int nhi = min(lo + cnt * step, hi);         // b[nhi] >= target
        lo = nlo; hi = nhi;
    }
    return lo;
}

__global__ __launch_bounds__(256) void fused_gcn(
    const float* __restrict__ x, const int* __restrict__ batch32,
    const float* __restrict__ W1, const float* __restrict__ b1,
    const float* __restrict__ W2, const float* __restrict__ b2,
    const float* __restrict__ Wc, const float* __restrict__ bc,
    float* __restrict__ out, int N)
{
    const int g    = blockIdx.x;
    const int tid  = threadIdx.x;
    const int lane = tid & 63;
    const int wv   = tid >> 6;

    __shared__ int   sStart, sEnd;
    __shared__ f4    part[256];      // also serves as the 128-float graph sum
    __shared__ float sH[HDIM];
    __shared__ float sRed[4];
    __shared__ float sCval;

    // waves 0/1 find [start,end) concurrently; waves 2/3 idle ~0.5us
    if (wv < 2) {
        const int is64 = detect_is64(batch32, N);
        int r = wave_lower_bound(batch32, is64, N, g + wv, lane);
        if (lane == 0) { if (wv == 0) sStart = r; else sEnd = r; }
    }
    __syncthreads();

    const int start = sStart, end = sEnd;

    // ---- streaming segment sum of this graph's rows -----------------------
    // thread (r, c4): rows start+r, +8, +16, ... column float4 c4.
    const int r  = tid >> 5;     // 0..7 row group
    const int c4 = tid & 31;     // float4 column
    const f4* x4 = (const f4*)x;
    f4 a0 = (f4){0.f, 0.f, 0.f, 0.f};
    f4 a1 = (f4){0.f, 0.f, 0.f, 0.f};
    f4 a2 = (f4){0.f, 0.f, 0.f, 0.f};
    f4 a3 = (f4){0.f, 0.f, 0.f, 0.f};
    int row = start + r;
    for (; row + 24 < end; row += 32) {           // 4 loads in flight
        f4 v0 = __builtin_nontemporal_load(&x4[row * 32 + c4]);
        f4 v1 = __builtin_nontemporal_load(&x4[(row + 8) * 32 + c4]);
        f4 v2 = __builtin_nontemporal_load(&x4[(row + 16) * 32 + c4]);
        f4 v3 = __builtin_nontemporal_load(&x4[(row + 24) * 32 + c4]);
        a0 += v0; a1 += v1; a2 += v2; a3 += v3;
    }
    for (; row < end; row += 8) {
        f4 v0 = __builtin_nontemporal_load(&x4[row * 32 + c4]);
        a0 += v0;
    }
    a0 += a1 + a2 + a3;

    part[tid] = a0;
    __syncthreads();
    for (int s = 4; s >= 1; s >>= 1) {            // reduce over row groups
        if (r < s) {
            part[tid] += part[tid + s * 32];
        }
        __syncthreads();
    }
    // part[0..31] as floats == the 128-element graph sum s, in feature order
    const float* sS = (const float*)part;

    // ---- MLP: thread tid owns h-column tid ---------------------------------
    float acc1 = b1[tid];
    #pragma unroll 16
    for (int k = 0; k < D; ++k)
        acc1 = fmaf(sS[k], W1[k * HDIM + tid], acc1);
    const float cnt = (float)(end - start);
    sH[tid] = fmaxf(acc1, 0.f) * cnt;             // agg(h1) = count * h1
    __syncthreads();

    float acc2 = b2[tid];
    #pragma unroll 16
    for (int k = 0; k < HDIM; ++k)
        acc2 = fmaf(sH[k], W2[k * HDIM + tid], acc2);

    float v = fmaxf(acc2, 0.f) * Wc[tid];
    for (int off = 32; off > 0; off >>= 1)
        v += __shfl_down(v, off, 64);
    if (lane == 0) sRed[wv] = v;
    __syncthreads();
    if (tid == 0) {
        float cc = sRed[0] + sRed[1] + sRed[2] + sRed[3] + bc[0];
        float m  = fmaxf(cc, 0.f);                 // stable softplus
        float sp = m + log1pf(expf(-fabsf(cc)));
        sCval = sp / (1.f + sp);
    }
    __syncthreads();

    // ---- coalesced scatter over this graph's contiguous span ---------------
    const float val = sCval;
    for (int i = start + tid; i < end; i += 256)
        out[i] = val;
}

extern "C" void kernel_launch(void* const* d_in, const int* in_sizes, int n_in,
                              void* d_out, int out_size, void* d_ws, size_t ws_size,
                              hipStream_t stream)
{
    const float* x   = (const float*)d_in[0];
    const int*   bat = (const int*)d_in[1];
    const float* W1  = (const float*)d_in[2];
    const float* b1  = (const float*)d_in[3];
    const float* W2  = (const float*)d_in[4];
    const float* b2  = (const float*)d_in[5];
    const float* Wc  = (const float*)d_in[6];
    const float* bc  = (const float*)d_in[7];
    float* out = (float*)d_out;
    const int N = in_sizes[0] / D;   // 100000 (same computation as proven kernel)

    (void)d_ws; (void)ws_size;       // workspace no longer used

    fused_gcn<<<NUM_GRAPHS, 256, 0, stream>>>(x, bat, W1, b1, W2, b2, Wc, bc,
                                              out, N);
}